// Round 6
// baseline (128.872 us; speedup 1.0000x reference)
//
#include <hip/hip_runtime.h>
#include <stdint.h>

// ---- problem constants ----
#define NPIX   4194304      // 8*512*1024
#define NGRP   (NPIX / 4)   // float4 groups
#define KSEL   1258291      // int(NPIX * 0.3)
#define HWSZ   524288       // 512*1024 (class-plane stride in elements)
#define NCLS   20

#define CE_BLOCKS 1024      // 1024 groups (4096 px) per block, all in one batch
#define H1_BLOCKS 256
#define H2_BLOCKS 512
#define H2_ITERS  8         // NGRP / (H2_BLOCKS*256)

// ---- workspace layout (bytes) ----
#define OFF_H1   0          // uint[2048]   level-1 histogram (bits 31..21)
#define OFF_H2   8192       // uint[2048]   level-2 histogram (bits 20..10, within b1)
#define OFF_S2   16384      // double[2048] level-2 per-bin value sums
#define OFF_SEL  32768      // uint[16]     {b1,k1}
#define OFF_PSUM 32832      // double[1024] per-block CE partial sums
#define OFF_B1P  49152      // double[512]  per-block definitely-top sums
#define OFF_CE   65536      // float[NPIX]  cached CE values
#define MEMSET_LEN 32768    // h1+h2+s2

typedef float  f4 __attribute__((ext_vector_type(4)));
typedef int    i4 __attribute__((ext_vector_type(4)));

__device__ __forceinline__ double block_reduce_d(double d, double* lred) {
    __syncthreads();  // protect lred reuse across calls
    for (int off = 32; off > 0; off >>= 1) d += __shfl_down(d, off);
    int wid  = threadIdx.x >> 6;
    int lane = threadIdx.x & 63;
    if (lane == 0) lred[wid] = d;
    __syncthreads();
    double r = 0.0;
    if (threadIdx.x == 0) {
        for (int i = 0; i < 4; ++i) r += lred[i];
    }
    return r;  // valid on thread 0 only
}

// find bin where descending suffix-count crosses ktar; writes *sbin,*skrem (one thread)
__device__ __forceinline__ void suffix_select(const unsigned* h, unsigned* tmp,
                                              unsigned ktar,
                                              unsigned* sbin, unsigned* skrem) {
    int t = threadIdx.x;
    unsigned lsum = 0;
#pragma unroll
    for (int j = 0; j < 8; ++j) lsum += h[t * 8 + j];
    tmp[t] = lsum;
    __syncthreads();
    for (int off = 1; off < 256; off <<= 1) {
        unsigned add = (t + off < 256) ? tmp[t + off] : 0u;
        __syncthreads();
        tmp[t] += add;
        __syncthreads();
    }
    unsigned cum = tmp[t] - lsum;   // count in bins strictly above my chunk
    for (int j = 7; j >= 0; --j) {
        unsigned hv = h[t * 8 + j];
        if (cum < ktar && cum + hv >= ktar) { *sbin = (unsigned)(t * 8 + j); *skrem = ktar - cum; }
        cum += hv;
    }
    __syncthreads();
}

// ---- kernel 1: per-pixel CE, class-outer / pixel-inner.
//      Block = 4096 contiguous pixels (one batch); per class-plane the block
//      streams 32 KB contiguous. 16 independent exp-chains per thread.
//      No LDS (occupancy VGPR-bound), no atomics. ----
__global__ __launch_bounds__(256) void ce_kernel(const float* __restrict__ pred,
                                                 const int* __restrict__ tgt,
                                                 float* __restrict__ ce,
                                                 double* __restrict__ psum) {
    __shared__ double lred[4];
    int t = threadIdx.x, blk = blockIdx.x;
    int g0 = blk * 1024;            // first float4-group of this block
    int p0 = g0 << 2;
    int b  = p0 >> 19;              // batch (4096 | 524288, so single batch/block)
    int hw = p0 & (HWSZ - 1);
    const float* base = pred + (size_t)b * (size_t)(NCLS * HWSZ) + hw;

    i4 tta[4];
#pragma unroll
    for (int it = 0; it < 4; ++it)
        tta[it] = __builtin_nontemporal_load((const i4*)tgt + (g0 + it * 256 + t));

    float s[16], vt[16];
#pragma unroll
    for (int i = 0; i < 16; ++i) { s[i] = 0.f; vt[i] = 0.f; }

#pragma unroll 4
    for (int c = 0; c < NCLS; ++c) {
        const f4* pc = (const f4*)(base + (size_t)c * HWSZ);
#pragma unroll
        for (int it = 0; it < 4; ++it) {
            f4 pv = __builtin_nontemporal_load(pc + it * 256 + t);
            s[it * 4 + 0] += __expf(pv.x);
            s[it * 4 + 1] += __expf(pv.y);
            s[it * 4 + 2] += __expf(pv.z);
            s[it * 4 + 3] += __expf(pv.w);
            if (c == tta[it].x) vt[it * 4 + 0] = pv.x;
            if (c == tta[it].y) vt[it * 4 + 1] = pv.y;
            if (c == tta[it].z) vt[it * 4 + 2] = pv.z;
            if (c == tta[it].w) vt[it * 4 + 3] = pv.w;
        }
    }

    double d = 0.0;
#pragma unroll
    for (int it = 0; it < 4; ++it) {
        f4 rr;
        // clamp at 0 keeps sign bit clear so uint bit-order == value order
        rr.x = fmaxf(__logf(s[it * 4 + 0]) - vt[it * 4 + 0], 0.0f);
        rr.y = fmaxf(__logf(s[it * 4 + 1]) - vt[it * 4 + 1], 0.0f);
        rr.z = fmaxf(__logf(s[it * 4 + 2]) - vt[it * 4 + 2], 0.0f);
        rr.w = fmaxf(__logf(s[it * 4 + 3]) - vt[it * 4 + 3], 0.0f);
        ((f4*)ce)[g0 + it * 256 + t] = rr;
        d += (double)rr.x + (double)rr.y + (double)rr.z + (double)rr.w;
    }
    d = block_reduce_d(d, lred);
    if (t == 0) psum[blk] = d;
}

// ---- kernel 2: level-1 histogram over CE bit patterns (L2/LLC-warm read) ----
__global__ __launch_bounds__(256) void hist1_kernel(const float* __restrict__ ce,
                                                    unsigned* __restrict__ h1) {
    __shared__ unsigned lh[4][2048];   // wave-private sub-histograms (32 KB)
    int t = threadIdx.x, w = t >> 6;
    for (int i = t; i < 4 * 2048; i += 256) ((unsigned*)lh)[i] = 0u;
    __syncthreads();
    const f4* ce4 = (const f4*)ce;
    int tid0 = blockIdx.x * 256 + t;
#pragma unroll
    for (int it = 0; it < 16; ++it) {
        f4 x = ce4[tid0 + it * (H1_BLOCKS * 256)];
        atomicAdd(&lh[w][__float_as_uint(x.x) >> 21], 1u);
        atomicAdd(&lh[w][__float_as_uint(x.y) >> 21], 1u);
        atomicAdd(&lh[w][__float_as_uint(x.z) >> 21], 1u);
        atomicAdd(&lh[w][__float_as_uint(x.w) >> 21], 1u);
    }
    __syncthreads();
    for (int i = t; i < 2048; i += 256) {
        unsigned c = lh[0][i] + lh[1][i] + lh[2][i] + lh[3][i];
        if (c) atomicAdd(&h1[i], c);
    }
}

// ---- kernel 3: redundant select-1 (per block, from L2-hot h1), then level-2
//      counts + per-bin double sums + definitely-top partial sum ----
__global__ __launch_bounds__(256) void hist2s_kernel(const unsigned* __restrict__ h1,
                                                     const float* __restrict__ ce,
                                                     unsigned* __restrict__ h2,
                                                     double* __restrict__ s2,
                                                     double* __restrict__ b1p,
                                                     unsigned* __restrict__ sel) {
    __shared__ unsigned hcnt[2048];   // h1 copy for scan, then level-2 counts
    __shared__ double   hsum[2048];   // level-2 value sums (16 KB)
    __shared__ unsigned tmp[256];
    __shared__ unsigned sbin, skrem;
    __shared__ double lred[4];
    int t = threadIdx.x, blk = blockIdx.x;

    for (int i = t; i < 2048; i += 256) hcnt[i] = h1[i];
    __syncthreads();
    suffix_select(hcnt, tmp, (unsigned)KSEL, &sbin, &skrem);
    unsigned b1 = sbin, k1 = skrem;
    if (blk == 0 && t == 0) { sel[0] = b1; sel[1] = k1; }

    for (int i = t; i < 2048; i += 256) { hcnt[i] = 0u; hsum[i] = 0.0; }
    __syncthreads();

    const f4* ce4 = (const f4*)ce;
    double big = 0.0;
    int tid0 = blk * 256 + t;
#pragma unroll
    for (int it = 0; it < H2_ITERS; ++it) {
        f4 x = ce4[tid0 + it * (H2_BLOCKS * 256)];
        float xs[4] = {x.x, x.y, x.z, x.w};
#pragma unroll
        for (int j = 0; j < 4; ++j) {
            unsigned u = __float_as_uint(xs[j]);
            unsigned hi = u >> 21;
            if (hi > b1) big += (double)xs[j];
            else if (hi == b1) {
                unsigned m = (u >> 10) & 0x7FFu;
                atomicAdd(&hcnt[m], 1u);
                atomicAdd(&hsum[m], (double)xs[j]);
            }
        }
    }
    __syncthreads();
    for (int i = t; i < 2048; i += 256) {
        if (hcnt[i]) atomicAdd(&h2[i], hcnt[i]);
        if (hsum[i] != 0.0) atomicAdd(&s2[i], hsum[i]);
    }
    big = block_reduce_d(big, lred);
    if (t == 0) b1p[blk] = big;
}

// ---- kernel 4: select-2 + finalize (one block) ----
__global__ __launch_bounds__(256) void fin_kernel(const unsigned* __restrict__ h2,
                                                  const unsigned* __restrict__ sel,
                                                  const double* __restrict__ psum,
                                                  const double* __restrict__ b1p,
                                                  const double* __restrict__ s2,
                                                  float* __restrict__ out) {
    __shared__ unsigned h[2048];
    __shared__ unsigned tmp[256];
    __shared__ unsigned sbin, skrem;
    __shared__ double lred[4];
    int t = threadIdx.x;

    for (int i = t; i < 2048; i += 256) h[i] = h2[i];
    __syncthreads();
    unsigned k1 = sel[1];
    suffix_select(h, tmp, k1, &sbin, &skrem);
    unsigned b2 = sbin, k2 = skrem;

    double a = 0.0;
    for (int i = t; i < CE_BLOCKS; i += 256) a += psum[i];
    double total = block_reduce_d(a, lred);

    double bg = 0.0;
    for (int i = t; i < H2_BLOCKS; i += 256) bg += b1p[i];
    double big = block_reduce_d(bg, lred);

    double sfx = 0.0;
    for (int i = t; i < 2048; i += 256) if (i > (int)b2) sfx += s2[i];
    double s2s = block_reduce_d(sfx, lred);

    if (t == 0) {
        // approximate boundary-tied elements by the level-2 bin's lower edge:
        // bin width <= 2^-13 * bin-base -> error < 0.004 vs threshold 0.16
        unsigned Tb = (sel[0] << 21) | (b2 << 10);
        double tv = (double)__uint_as_float(Tb);
        double top = big + s2s + (double)k2 * tv;
        double loss = total / ((double)NPIX + 1e-12) + top / (double)KSEL;
        out[0] = (float)loss;
    }
}

extern "C" void kernel_launch(void* const* d_in, const int* in_sizes, int n_in,
                              void* d_out, int out_size, void* d_ws, size_t ws_size,
                              hipStream_t stream) {
    const float* pred = (const float*)d_in[0];
    const int*   tgt  = (const int*)d_in[1];
    float* out = (float*)d_out;
    char* ws = (char*)d_ws;
    unsigned* h1   = (unsigned*)(ws + OFF_H1);
    unsigned* h2   = (unsigned*)(ws + OFF_H2);
    double*   s2   = (double*)(ws + OFF_S2);
    unsigned* sel  = (unsigned*)(ws + OFF_SEL);
    double*   psum = (double*)(ws + OFF_PSUM);
    double*   b1p  = (double*)(ws + OFF_B1P);
    float*    ce   = (float*)(ws + OFF_CE);

    hipMemsetAsync(ws + OFF_H1, 0, MEMSET_LEN, stream);
    ce_kernel<<<CE_BLOCKS, 256, 0, stream>>>(pred, tgt, ce, psum);
    hist1_kernel<<<H1_BLOCKS, 256, 0, stream>>>(ce, h1);
    hist2s_kernel<<<H2_BLOCKS, 256, 0, stream>>>(h1, ce, h2, s2, b1p, sel);
    fin_kernel<<<1, 256, 0, stream>>>(h2, sel, psum, b1p, s2, out);
}

// Round 7
// 109.055 us; speedup vs baseline: 1.1817x; 1.1817x over previous
//
#include <hip/hip_runtime.h>
#include <stdint.h>

// ---- problem constants ----
#define NPIX   4194304      // 8*512*1024
#define NGRP   (NPIX / 4)   // float4 groups
#define KSEL   1258291      // int(NPIX * 0.3)
#define HWSZ   524288       // 512*1024 (class-plane stride in elements)
#define NCLS   20

#define CE_BLOCKS 1024      // each block: 1024 consecutive float4-groups (4096 px)
#define H2_BLOCKS 1024
#define H2_ITERS  4         // NGRP / (H2_BLOCKS*256)

// ---- workspace layout (bytes) ----
#define OFF_H1   0          // uint[2048]   level-1 histogram (bits 31..21)
#define OFF_H2   8192       // uint[2048]   level-2 histogram (bits 20..10, within b1)
#define OFF_SEL  16384      // uint[16]     {b1,k1}
#define OFF_PSUM 16448      // double[1024] per-block CE partial sums
#define OFF_B1P  24640      // double[1024] per-block definitely-top sums
#define OFF_CE   65536      // float[NPIX]  cached CE values
#define MEMSET_LEN 16384    // h1+h2

typedef float  f4 __attribute__((ext_vector_type(4)));
typedef int    i4 __attribute__((ext_vector_type(4)));

__device__ __forceinline__ double block_reduce_d(double d, double* lred) {
    __syncthreads();  // protect lred reuse across calls
    for (int off = 32; off > 0; off >>= 1) d += __shfl_down(d, off);
    int wid  = threadIdx.x >> 6;
    int lane = threadIdx.x & 63;
    if (lane == 0) lred[wid] = d;
    __syncthreads();
    double r = 0.0;
    if (threadIdx.x == 0) {
        for (int i = 0; i < 4; ++i) r += lred[i];
    }
    return r;  // valid on thread 0 only
}

// find bin where descending suffix-count crosses ktar; writes *sbin,*skrem (one thread)
__device__ __forceinline__ void suffix_select(const unsigned* h, unsigned* tmp,
                                              unsigned ktar,
                                              unsigned* sbin, unsigned* skrem) {
    int t = threadIdx.x;
    unsigned lsum = 0;
#pragma unroll
    for (int j = 0; j < 8; ++j) lsum += h[t * 8 + j];
    tmp[t] = lsum;
    __syncthreads();
    for (int off = 1; off < 256; off <<= 1) {
        unsigned add = (t + off < 256) ? tmp[t + off] : 0u;
        __syncthreads();
        tmp[t] += add;
        __syncthreads();
    }
    unsigned cum = tmp[t] - lsum;   // count in bins strictly above my chunk
    for (int j = 7; j >= 0; --j) {
        unsigned hv = h[t * 8 + j];
        if (cum < ktar && cum + hv >= ktar) { *sbin = (unsigned)(t * 8 + j); *skrem = ktar - cum; }
        cum += hv;
    }
    __syncthreads();
}

// ---- kernel 1: per-pixel CE. Block = 1024 consecutive groups; per class each
//      WAVE reads 4 KB contiguous (4 lane-contiguous 1KB bursts). 16 independent
//      exp chains/thread. Fused wave-private level-1 histogram. ----
__global__ __launch_bounds__(256) void ce_kernel(const float* __restrict__ pred,
                                                 const int* __restrict__ tgt,
                                                 float* __restrict__ ce,
                                                 double* __restrict__ psum,
                                                 unsigned* __restrict__ h1) {
    __shared__ unsigned lh[4][2048];   // wave-private sub-histograms (32 KB)
    __shared__ double lred[4];
    int t = threadIdx.x, w = t >> 6, l = t & 63;
    for (int i = t; i < 4 * 2048; i += 256) ((unsigned*)lh)[i] = 0u;
    __syncthreads();

    int g0 = blockIdx.x << 10;      // first float4-group of this block
    int p0 = g0 << 2;
    int b  = p0 >> 19;              // batch index (4096 px/block divides 524288)
    int hw = p0 & (HWSZ - 1);
    const float* base = pred + (size_t)b * (size_t)(NCLS * HWSZ) + hw;

    // thread's 4 groups: wave w covers groups [w*256, w*256+256) contiguously
    int goff[4];
#pragma unroll
    for (int it = 0; it < 4; ++it) goff[it] = (w << 8) + (it << 6) + l;

    i4 tt[4];
#pragma unroll
    for (int it = 0; it < 4; ++it) tt[it] = ((const i4*)tgt)[g0 + goff[it]];

    float s[16], vt[16];
#pragma unroll
    for (int i = 0; i < 16; ++i) { s[i] = 0.f; vt[i] = 0.f; }

#pragma unroll
    for (int c = 0; c < NCLS; ++c) {
        const f4* pc = (const f4*)(base + (size_t)c * HWSZ);
#pragma unroll
        for (int it = 0; it < 4; ++it) {
            f4 pv = pc[goff[it]];
            s[it * 4 + 0] += __expf(pv.x);
            s[it * 4 + 1] += __expf(pv.y);
            s[it * 4 + 2] += __expf(pv.z);
            s[it * 4 + 3] += __expf(pv.w);
            if (c == tt[it].x) vt[it * 4 + 0] = pv.x;
            if (c == tt[it].y) vt[it * 4 + 1] = pv.y;
            if (c == tt[it].z) vt[it * 4 + 2] = pv.z;
            if (c == tt[it].w) vt[it * 4 + 3] = pv.w;
        }
    }

    double d = 0.0;
#pragma unroll
    for (int it = 0; it < 4; ++it) {
        f4 rr;
        // clamp at 0 keeps sign bit clear so uint bit-order == value order
        rr.x = fmaxf(__logf(s[it * 4 + 0]) - vt[it * 4 + 0], 0.0f);
        rr.y = fmaxf(__logf(s[it * 4 + 1]) - vt[it * 4 + 1], 0.0f);
        rr.z = fmaxf(__logf(s[it * 4 + 2]) - vt[it * 4 + 2], 0.0f);
        rr.w = fmaxf(__logf(s[it * 4 + 3]) - vt[it * 4 + 3], 0.0f);
        ((f4*)ce)[g0 + goff[it]] = rr;
        d += (double)rr.x + (double)rr.y + (double)rr.z + (double)rr.w;
        atomicAdd(&lh[w][__float_as_uint(rr.x) >> 21], 1u);
        atomicAdd(&lh[w][__float_as_uint(rr.y) >> 21], 1u);
        atomicAdd(&lh[w][__float_as_uint(rr.z) >> 21], 1u);
        atomicAdd(&lh[w][__float_as_uint(rr.w) >> 21], 1u);
    }
    __syncthreads();
    for (int i = t; i < 2048; i += 256) {
        unsigned c = lh[0][i] + lh[1][i] + lh[2][i] + lh[3][i];
        if (c) atomicAdd(&h1[i], c);
    }
    d = block_reduce_d(d, lred);
    if (t == 0) psum[blockIdx.x] = d;
}

// ---- kernel 2: redundant select-1 (per block, L2-hot h1), then level-2 COUNTS
//      (uint LDS atomics only) + exact register big-sum for bins > b1 ----
__global__ __launch_bounds__(256) void hist2big_kernel(const unsigned* __restrict__ h1,
                                                       const float* __restrict__ ce,
                                                       unsigned* __restrict__ h2,
                                                       double* __restrict__ b1p,
                                                       unsigned* __restrict__ sel) {
    __shared__ unsigned hcnt[2048];   // h1 copy for scan, then level-2 counts
    __shared__ unsigned tmp[256];
    __shared__ unsigned sbin, skrem;
    __shared__ double lred[4];
    int t = threadIdx.x, blk = blockIdx.x;

    for (int i = t; i < 2048; i += 256) hcnt[i] = h1[i];
    __syncthreads();
    suffix_select(hcnt, tmp, (unsigned)KSEL, &sbin, &skrem);
    unsigned b1 = sbin, k1 = skrem;
    if (blk == 0 && t == 0) { sel[0] = b1; sel[1] = k1; }

    for (int i = t; i < 2048; i += 256) hcnt[i] = 0u;
    __syncthreads();

    const f4* ce4 = (const f4*)ce;
    double big = 0.0;
    int tid0 = blk * 256 + t;
#pragma unroll
    for (int it = 0; it < H2_ITERS; ++it) {
        f4 x = ce4[tid0 + it * (H2_BLOCKS * 256)];
        float xs[4] = {x.x, x.y, x.z, x.w};
#pragma unroll
        for (int j = 0; j < 4; ++j) {
            unsigned u = __float_as_uint(xs[j]);
            unsigned hi = u >> 21;
            if (hi > b1) big += (double)xs[j];
            else if (hi == b1) atomicAdd(&hcnt[(u >> 10) & 0x7FFu], 1u);
        }
    }
    __syncthreads();
    for (int i = t; i < 2048; i += 256) {
        if (hcnt[i]) atomicAdd(&h2[i], hcnt[i]);
    }
    big = block_reduce_d(big, lred);
    if (t == 0) b1p[blk] = big;
}

// ---- kernel 3: select-2 + finalize via per-bin edge weighting (one block) ----
__global__ __launch_bounds__(256) void fin_kernel(const unsigned* __restrict__ h2,
                                                  const unsigned* __restrict__ sel,
                                                  const double* __restrict__ psum,
                                                  const double* __restrict__ b1p,
                                                  float* __restrict__ out) {
    __shared__ unsigned h[2048];
    __shared__ unsigned tmp[256];
    __shared__ unsigned sbin, skrem;
    __shared__ double lred[4];
    int t = threadIdx.x;

    for (int i = t; i < 2048; i += 256) h[i] = h2[i];
    __syncthreads();
    unsigned b1 = sel[0], k1 = sel[1];
    suffix_select(h, tmp, k1, &sbin, &skrem);
    unsigned b2 = sbin, k2 = skrem;

    double a = 0.0;
    for (int i = t; i < CE_BLOCKS; i += 256) a += psum[i];
    double total = block_reduce_d(a, lred);

    double bg = 0.0;
    for (int i = t; i < H2_BLOCKS; i += 256) bg += b1p[i];
    double bigs = block_reduce_d(bg, lred);

    // b1-bin contribution: count-weighted level-2 bin lower edges
    // (per-element error <= bin width ~ 2^-13 relative — far below threshold)
    double es = 0.0;
    for (int i = t; i < 2048; i += 256)
        if (i > (int)b2)
            es += (double)h[i] * (double)__uint_as_float((b1 << 21) | ((unsigned)i << 10));
    double l2s = block_reduce_d(es, lred);

    if (t == 0) {
        double tv = (double)__uint_as_float((b1 << 21) | (b2 << 10));
        double top = bigs + l2s + (double)k2 * tv;
        double loss = total / ((double)NPIX + 1e-12) + top / (double)KSEL;
        out[0] = (float)loss;
    }
}

extern "C" void kernel_launch(void* const* d_in, const int* in_sizes, int n_in,
                              void* d_out, int out_size, void* d_ws, size_t ws_size,
                              hipStream_t stream) {
    const float* pred = (const float*)d_in[0];
    const int*   tgt  = (const int*)d_in[1];
    float* out = (float*)d_out;
    char* ws = (char*)d_ws;
    unsigned* h1   = (unsigned*)(ws + OFF_H1);
    unsigned* h2   = (unsigned*)(ws + OFF_H2);
    unsigned* sel  = (unsigned*)(ws + OFF_SEL);
    double*   psum = (double*)(ws + OFF_PSUM);
    double*   b1p  = (double*)(ws + OFF_B1P);
    float*    ce   = (float*)(ws + OFF_CE);

    hipMemsetAsync(ws + OFF_H1, 0, MEMSET_LEN, stream);
    ce_kernel<<<CE_BLOCKS, 256, 0, stream>>>(pred, tgt, ce, psum, h1);
    hist2big_kernel<<<H2_BLOCKS, 256, 0, stream>>>(h1, ce, h2, b1p, sel);
    fin_kernel<<<1, 256, 0, stream>>>(h2, sel, psum, b1p, out);
}